// Round 9
// baseline (472.020 us; speedup 1.0000x reference)
//
#include <hip/hip_runtime.h>
#include <hip/hip_cooperative_groups.h>
#include <hip/hip_bf16.h>
#include <math.h>

namespace cg = cooperative_groups;

#define C 128
#define SIM_THRESH 0.2f
#define DEG_THRESH 3.0f

// Packed segment-sum: one u64 per node. v += (1<<40) + round(e * 2^24).
// deg = (v + 2^39) >> 40 (exact); csum = (v - deg<<40) * 2^-24.
#define FIX_SCALE 16777216.0f            // 2^24
#define FIX_INV   5.9604644775390625e-8f // 2^-24

typedef float floatx2 __attribute__((ext_vector_type(2)));

struct Params {
    const float *x, *ps, *pd, *po, *ro, *W, *b, *Wo, *bo;
    const int *ei;
    unsigned int *xn;
    unsigned long long *packed;
    float *qb, *kb, *vpb, *finals, *out;
    int N, E;
};

// ---------------------------------------------------------------------------
// Depth-1 wave-group GEMV (36 logical blocks; blk = g*4 + qt):
//   g==0   : qb[t]      = b[t]    + readout . W[t]
//   g 1..4 : kb[g-1][t] = b[C+t]  + base . W[C+t]
//   g 5..8 : v[t]       = b[2C+t] + base . W[2C+t] (full 128 -> LDS)
//            vpb[g-5][t]= v . Wo[t]
// Each dot: 8-lane group, 4 independent float4 loads/lane + 3 shuffles.
// ---------------------------------------------------------------------------
__device__ __forceinline__ void gemv_body(int blk,
        const float* __restrict__ ps, const float* __restrict__ pd,
        const float* __restrict__ po, const float* __restrict__ ro,
        const float* __restrict__ W,  const float* __restrict__ b,
        const float* __restrict__ Wo,
        float* __restrict__ qb, float* __restrict__ kb, float* __restrict__ vpb) {
    int g  = blk >> 2;
    int qt = blk & 3;
    int gi = threadIdx.x >> 3;
    int li = threadIdx.x & 7;

    int bi = (g == 0) ? 0 : (g <= 4 ? g - 1 : g - 5);
    const float* src = (bi == 0) ? ro : (bi == 1 ? ps : (bi == 2 ? pd : po));
    float4 s4[4];
    #pragma unroll
    for (int k = 0; k < 4; ++k) s4[k] = ((const float4*)src)[8 * k + li];

    if (g <= 4) {
        int rowoff = (g == 0) ? 0 : C;
        int t = qt * 32 + gi;
        const float* Wr = W + (size_t)(rowoff + t) * C;
        float p = 0.0f;
        #pragma unroll
        for (int k = 0; k < 4; ++k) {
            float4 w4 = ((const float4*)Wr)[8 * k + li];
            p += w4.x * s4[k].x + w4.y * s4[k].y + w4.z * s4[k].z + w4.w * s4[k].w;
        }
        p += __shfl_xor(p, 1, 64);
        p += __shfl_xor(p, 2, 64);
        p += __shfl_xor(p, 4, 64);
        if (li == 0) {
            if (g == 0) qb[t] = p + b[t];
            else        kb[(g - 1) * C + t] = p + b[C + t];
        }
    } else {
        __shared__ float vbuf[C];
        #pragma unroll
        for (int j = 0; j < 4; ++j) {
            int t = gi + 32 * j;
            const float* Wr = W + (size_t)(2 * C + t) * C;
            float p = 0.0f;
            #pragma unroll
            for (int k = 0; k < 4; ++k) {
                float4 w4 = ((const float4*)Wr)[8 * k + li];
                p += w4.x * s4[k].x + w4.y * s4[k].y + w4.z * s4[k].z + w4.w * s4[k].w;
            }
            p += __shfl_xor(p, 1, 64);
            p += __shfl_xor(p, 2, 64);
            p += __shfl_xor(p, 4, 64);
            if (li == 0) vbuf[t] = p + b[2 * C + t];
        }
        __syncthreads();
        float4 v4[4];
        #pragma unroll
        for (int k = 0; k < 4; ++k) v4[k] = ((const float4*)vbuf)[8 * k + li];
        int t = qt * 32 + gi;
        const float* Wr = Wo + (size_t)t * C;
        float p = 0.0f;
        #pragma unroll
        for (int k = 0; k < 4; ++k) {
            float4 w4 = ((const float4*)Wr)[8 * k + li];
            p += w4.x * v4[k].x + w4.y * v4[k].y + w4.z * v4[k].z + w4.w * v4[k].w;
        }
        p += __shfl_xor(p, 1, 64);
        p += __shfl_xor(p, 2, 64);
        p += __shfl_xor(p, 4, 64);
        if (li == 0) vpb[(g - 5) * C + t] = p;
    }
}

// ---------------------------------------------------------------------------
// combine: 4 q.k dots, per-combo softmax, finals[combo] = bo + sum attn*vpb.
// ---------------------------------------------------------------------------
__device__ __forceinline__ void combine_body(
        const float* __restrict__ qb, const float* __restrict__ kb,
        const float* __restrict__ vpb, const float* __restrict__ bo,
        float* __restrict__ finals) {
    __shared__ float attn_s[4][4];
    int wv = threadIdx.x >> 6;
    int lane = threadIdx.x & 63;
    if (wv == 0) {
        float2 qv = ((const float2*)qb)[lane];
        float d[4];
        #pragma unroll
        for (int bI = 0; bI < 4; ++bI) {
            float2 kv = ((const float2*)(kb + bI * C))[lane];
            float p = qv.x * kv.x + qv.y * kv.y;
            #pragma unroll
            for (int off = 32; off; off >>= 1) p += __shfl_xor(p, off, 64);
            d[bI] = p;
        }
        if (lane == 0) {
            const float scale = 0.08838834764831845f; // 1/sqrt(128)
            for (int combo = 0; combo < 4; ++combo) {
                bool sim = (combo & 1), degm = (combo & 2), other = !(sim || degm);
                bool act[4] = { true, sim, degm, other };
                float m = -INFINITY;
                #pragma unroll
                for (int j = 0; j < 4; ++j) if (act[j]) m = fmaxf(m, d[j] * scale);
                float w[4], den = 0.0f;
                #pragma unroll
                for (int j = 0; j < 4; ++j) {
                    w[j] = act[j] ? expf(d[j] * scale - m) : 0.0f;
                    den += w[j];
                }
                #pragma unroll
                for (int j = 0; j < 4; ++j) attn_s[combo][j] = w[j] / den;
            }
        }
    }
    __syncthreads();
    int t = threadIdx.x;
    if (t < C) {
        for (int combo = 0; combo < 4; ++combo) {
            float f = bo[t];
            #pragma unroll
            for (int j = 0; j < 4; ++j) f += attn_s[combo][j] * vpb[j * C + t];
            finals[combo * C + t] = f;
        }
    }
}

// ---------------------------------------------------------------------------
// Cooperative mega-kernel: P0 {gemv + norm/fp8 + packed=0} | sync |
// P1 {combine + edges} | sync | P2 {apply}. Grid-stride everywhere.
// ---------------------------------------------------------------------------
__global__ __launch_bounds__(256, 4) void fused_kernel(Params P) {
    cg::grid_group grid = cg::this_grid();
    const int bid = blockIdx.x;
    const int tid = threadIdx.x;
    const int nb  = gridDim.x;

    // ---- Phase 0 ----
    if (bid < 36)
        gemv_body(bid, P.ps, P.pd, P.po, P.ro, P.W, P.b, P.Wo, P.qb, P.kb, P.vpb);
    {
        int grp = tid >> 5, l = tid & 31;
        for (int row = bid * 8 + grp; row < P.N; row += nb * 8) {
            float4 a = ((const float4*)(P.x + (size_t)row * C))[l];
            float s = a.x * a.x + a.y * a.y + a.z * a.z + a.w * a.w;
            #pragma unroll
            for (int off = 16; off; off >>= 1) s += __shfl_xor(s, off, 64);
            float r = rsqrtf(s);
            int u = __builtin_amdgcn_cvt_pk_fp8_f32(a.x * r, a.y * r, 0, false);
            u     = __builtin_amdgcn_cvt_pk_fp8_f32(a.z * r, a.w * r, u, true);
            P.xn[(size_t)row * 32 + l] = (unsigned int)u;
            if (l == 0) P.packed[row] = 0ULL;
        }
    }
    grid.sync();

    // ---- Phase 1 ----
    if (bid == 0) combine_body(P.qb, P.kb, P.vpb, P.bo, P.finals);
    {
        const uint4* xn4 = (const uint4*)P.xn;
        int lane = tid & 7;
        int step = (nb * 256) >> 3;
        for (int e = (bid * 256 + tid) >> 3; e < P.E; e += step) {
            int r = P.ei[e];
            int c = P.ei[P.E + e];
            uint4 a = xn4[(size_t)r * 8 + lane];
            uint4 b = xn4[(size_t)c * 8 + lane];
            float dot = 0.0f;
            #pragma unroll
            for (int k = 0; k < 4; ++k) {
                int ua = (int)(&a.x)[k], ub = (int)(&b.x)[k];
                floatx2 a0 = __builtin_amdgcn_cvt_pk_f32_fp8(ua, false);
                floatx2 a1 = __builtin_amdgcn_cvt_pk_f32_fp8(ua, true);
                floatx2 b0 = __builtin_amdgcn_cvt_pk_f32_fp8(ub, false);
                floatx2 b1 = __builtin_amdgcn_cvt_pk_f32_fp8(ub, true);
                dot += a0.x * b0.x + a0.y * b0.y + a1.x * b1.x + a1.y * b1.y;
            }
            dot += __shfl_xor(dot, 1, 64);
            dot += __shfl_xor(dot, 2, 64);
            dot += __shfl_xor(dot, 4, 64);
            if (lane == 0) {
                long long fx = (long long)llrintf(dot * FIX_SCALE);
                atomicAdd(&P.packed[c], (1ULL << 40) + (unsigned long long)fx);
            }
        }
    }
    grid.sync();

    // ---- Phase 2 ----
    {
        size_t total = (size_t)P.N * 32;
        for (size_t i = (size_t)bid * 256 + tid; i < total; i += (size_t)nb * 256) {
            int row = (int)(i >> 5);
            unsigned long long v = P.packed[row];
            long long d_ll = (long long)((v + (1ULL << 39)) >> 40);
            long long s_ll = (long long)(v - ((unsigned long long)d_ll << 40));
            float d  = (float)d_ll;
            float cs = (float)s_ll * FIX_INV;
            bool sim  = (d_ll > 0) && ((cs / d) <= SIM_THRESH);
            bool degm = d <= DEG_THRESH;
            int combo = (sim ? 1 : 0) | (degm ? 2 : 0);
            float4 xv = ((const float4*)P.x)[i];
            float4 fv = ((const float4*)P.finals)[(size_t)combo * 32 + (i & 31)];
            float4 o  = { xv.x + fv.x, xv.y + fv.y, xv.z + fv.z, xv.w + fv.w };
            ((float4*)P.out)[i] = o;
        }
    }
}

// ---------------------------------------------------------------------------
// Fallback non-cooperative path (R7 structure).
// ---------------------------------------------------------------------------
__global__ void prep_kernel(const float* __restrict__ x, unsigned int* __restrict__ xn,
                            unsigned long long* __restrict__ packed,
                            const float* __restrict__ ps, const float* __restrict__ pd,
                            const float* __restrict__ po, const float* __restrict__ ro,
                            const float* __restrict__ W,  const float* __restrict__ b,
                            const float* __restrict__ Wo,
                            float* __restrict__ qb, float* __restrict__ kb,
                            float* __restrict__ vpb, int N) {
    if (blockIdx.x < 36) {
        gemv_body(blockIdx.x, ps, pd, po, ro, W, b, Wo, qb, kb, vpb);
        return;
    }
    int grp = threadIdx.x >> 5;
    int l   = threadIdx.x & 31;
    int row = (blockIdx.x - 36) * 8 + grp;
    if (row >= N) return;
    float4 a = ((const float4*)(x + (size_t)row * C))[l];
    float s = a.x * a.x + a.y * a.y + a.z * a.z + a.w * a.w;
    #pragma unroll
    for (int off = 16; off; off >>= 1) s += __shfl_xor(s, off, 64);
    float r = rsqrtf(s);
    int u = __builtin_amdgcn_cvt_pk_fp8_f32(a.x * r, a.y * r, 0, false);
    u     = __builtin_amdgcn_cvt_pk_fp8_f32(a.z * r, a.w * r, u, true);
    xn[(size_t)row * 32 + l] = (unsigned int)u;
    if (l == 0) packed[row] = 0ULL;
}

__global__ void edge_kernel_fp8(const uint4* __restrict__ xn4, const int* __restrict__ ei,
                                unsigned long long* __restrict__ packed, int E,
                                const float* __restrict__ qb, const float* __restrict__ kb,
                                const float* __restrict__ vpb, const float* __restrict__ bo,
                                float* __restrict__ finals) {
    if (blockIdx.x == 0) {
        combine_body(qb, kb, vpb, bo, finals);
        return;
    }
    int gid  = (blockIdx.x - 1) * blockDim.x + threadIdx.x;
    int edge = gid >> 3;
    int lane = threadIdx.x & 7;
    if (edge >= E) return;
    int r = ei[edge];
    int c = ei[E + edge];
    uint4 a = xn4[(size_t)r * 8 + lane];
    uint4 b = xn4[(size_t)c * 8 + lane];
    float dot = 0.0f;
    #pragma unroll
    for (int k = 0; k < 4; ++k) {
        int ua = (int)(&a.x)[k], ub = (int)(&b.x)[k];
        floatx2 a0 = __builtin_amdgcn_cvt_pk_f32_fp8(ua, false);
        floatx2 a1 = __builtin_amdgcn_cvt_pk_f32_fp8(ua, true);
        floatx2 b0 = __builtin_amdgcn_cvt_pk_f32_fp8(ub, false);
        floatx2 b1 = __builtin_amdgcn_cvt_pk_f32_fp8(ub, true);
        dot += a0.x * b0.x + a0.y * b0.y + a1.x * b1.x + a1.y * b1.y;
    }
    #pragma unroll
    for (int off = 4; off; off >>= 1) dot += __shfl_xor(dot, off, 64);
    if (lane == 0) {
        long long fx = (long long)llrintf(dot * FIX_SCALE);
        atomicAdd(&packed[c], (1ULL << 40) + (unsigned long long)fx);
    }
}

__global__ void apply_kernel(const float* __restrict__ x,
                             const unsigned long long* __restrict__ packed,
                             const float* __restrict__ finals,
                             float* __restrict__ out, int N) {
    size_t i = (size_t)blockIdx.x * blockDim.x + threadIdx.x;
    size_t total = (size_t)N * (C / 4);
    if (i >= total) return;
    int row = (int)(i >> 5);
    unsigned long long v = packed[row];
    long long d_ll = (long long)((v + (1ULL << 39)) >> 40);
    long long s_ll = (long long)(v - ((unsigned long long)d_ll << 40));
    float d  = (float)d_ll;
    float cs = (float)s_ll * FIX_INV;
    bool sim  = (d_ll > 0) && ((cs / d) <= SIM_THRESH);
    bool degm = d <= DEG_THRESH;
    int combo = (sim ? 1 : 0) | (degm ? 2 : 0);
    float4 xv = ((const float4*)x)[i];
    float4 fv = ((const float4*)finals)[(size_t)combo * 32 + (i & 31)];
    float4 o  = { xv.x + fv.x, xv.y + fv.y, xv.z + fv.z, xv.w + fv.w };
    ((float4*)out)[i] = o;
}

extern "C" void kernel_launch(void* const* d_in, const int* in_sizes, int n_in,
                              void* d_out, int out_size, void* d_ws, size_t ws_size,
                              hipStream_t stream) {
    Params P;
    P.x  = (const float*)d_in[0];
    P.ps = (const float*)d_in[1];
    P.pd = (const float*)d_in[2];
    P.po = (const float*)d_in[3];
    P.ro = (const float*)d_in[4];
    P.W  = (const float*)d_in[5];
    P.b  = (const float*)d_in[6];
    P.Wo = (const float*)d_in[7];
    P.bo = (const float*)d_in[8];
    P.ei = (const int*)d_in[9];
    P.N  = in_sizes[0] / C;
    P.E  = in_sizes[9] / 2;
    P.out = (float*)d_out;

    // ws: [packed N*u64][finals 512f][qb 128f][kb 512f][vpb 512f][align][xn N*128B]
    P.packed = (unsigned long long*)d_ws;
    P.finals = (float*)(P.packed + P.N);
    P.qb     = P.finals + 4 * C;
    P.kb     = P.qb + C;
    P.vpb    = P.kb + 4 * C;
    size_t head_bytes = ((size_t)P.N * 8 + (size_t)(13 * C) * sizeof(float) + 255) & ~(size_t)255;
    P.xn = (unsigned int*)((char*)d_ws + head_bytes);

    int coop = 0;
    hipDeviceGetAttribute(&coop, hipDeviceAttributeCooperativeLaunch, 0);

    if (coop) {
        void* args[] = { (void*)&P };
        hipLaunchCooperativeKernel((const void*)fused_kernel, dim3(1024), dim3(256),
                                   args, 0, stream);
    } else {
        {
            int nRowBlocks = (P.N + 7) / 8;
            prep_kernel<<<nRowBlocks + 36, 256, 0, stream>>>(
                P.x, P.xn, P.packed, P.ps, P.pd, P.po, P.ro,
                P.W, P.b, P.Wo, P.qb, P.kb, P.vpb, P.N);
        }
        {
            long long lanes = (long long)P.E * 8;
            int blocks = 1 + (int)((lanes + 255) / 256);
            edge_kernel_fp8<<<blocks, 256, 0, stream>>>((const uint4*)P.xn, P.ei, P.packed, P.E,
                                                        P.qb, P.kb, P.vpb, P.bo, P.finals);
        }
        {
            long long work = (long long)P.N * (C / 4);
            int blocks = (int)((work + 255) / 256);
            apply_kernel<<<blocks, 256, 0, stream>>>(P.x, P.packed, P.finals, P.out, P.N);
        }
    }
}